// Round 4
// baseline (59.912 us; speedup 1.0000x reference)
//
#include <hip/hip_runtime.h>
#include <stdint.h>

#define IN_F 8192
#define OUT_F 8192
#define BATCH 8
#define XPW 2048  // packed x sign words (8 KB LDS)

typedef unsigned int u32x4 __attribute__((ext_vector_type(4)));

// Single fused kernel. One wave per output row (4 rows/block, 2048 blocks).
//
// Phase 1 (no deps): stream this wave's W row via nontemporal uint4 loads,
//   compress to 4x32 sign bits in registers (wn[m], bit 4i+k = sign of
//   element m*2048 + i*256 + lane*4 + k).
// Phase 2 (L2-resident x): block-redundant pack of x into LDS with the
//   matching layout: xl[(b*4+m)*64 + lane], bit 4i+k = sign(x[b][m*2048+i*256+lane*4+k]).
// Phase 3: cnt[b] += popc(wn[m] ^ xl[...]) ; wave shuffle-reduce; lane 0
//   writes out[b][row] = 8192 - 2*cnt + bias[row].
__global__ __launch_bounds__(256) void ternary_fused(
    const u32x4* __restrict__ W, const u32x4* __restrict__ x,
    const float* __restrict__ bias, float* __restrict__ out) {
  __shared__ uint32_t xl[XPW];

  const int warp = threadIdx.x >> 6;
  const int lane = threadIdx.x & 63;
  const int row = blockIdx.x * 4 + warp;
  const u32x4* wrow = W + (size_t)row * (IN_F / 4);

  // ---- Phase 1: W row -> 4x32 sign bits in registers (HBM stream, NT) ----
  uint32_t wn[4];
#pragma unroll
  for (int m = 0; m < 4; ++m) {
    u32x4 u[8];
#pragma unroll
    for (int i = 0; i < 8; ++i)
      u[i] = __builtin_nontemporal_load(&wrow[m * 512 + i * 64 + lane]);
    uint32_t v = 0;
#pragma unroll
    for (int i = 0; i < 8; ++i) {
      uint32_t nib = (u[i].x >> 31) | ((u[i].y >> 31) << 1) |
                     ((u[i].z >> 31) << 2) | ((u[i].w >> 31) << 3);
      v |= nib << (4 * i);
    }
    wn[m] = v;
  }

  // ---- Phase 2: redundant x pack into LDS (x is L2-resident, 256 KB) ----
  // Thread (warp, lane), j=0..7 produces word bm = j*4 + warp at its lane:
  // quad address (uint4 units) = b*2048 + m*512 + i*64 + lane = bm*512 + i*64 + lane.
#pragma unroll
  for (int j = 0; j < 8; ++j) {
    const int bm = j * 4 + warp;
    const u32x4* base = x + bm * 512 + lane;
    uint32_t v = 0;
#pragma unroll
    for (int i = 0; i < 8; ++i) {
      u32x4 u = base[i * 64];
      uint32_t nib = (u.x >> 31) | ((u.y >> 31) << 1) |
                     ((u.z >> 31) << 2) | ((u.w >> 31) << 3);
      v |= nib << (4 * i);
    }
    xl[bm * 64 + lane] = v;
  }
  __syncthreads();

  // ---- Phase 3: xor + popcount accumulate ----
  int cnt[BATCH] = {0, 0, 0, 0, 0, 0, 0, 0};
#pragma unroll
  for (int m = 0; m < 4; ++m) {
#pragma unroll
    for (int b = 0; b < BATCH; ++b)
      cnt[b] += __popc(wn[m] ^ xl[(b * 4 + m) * 64 + lane]);
  }

  // Wave-level reduce of the 8 mismatch counts.
#pragma unroll
  for (int b = 0; b < BATCH; ++b) {
#pragma unroll
    for (int off = 32; off > 0; off >>= 1)
      cnt[b] += __shfl_down(cnt[b], off);
  }

  if (lane == 0) {
    const float bv = bias[row];
#pragma unroll
    for (int b = 0; b < BATCH; ++b)
      out[(size_t)b * OUT_F + row] = (float)(IN_F - 2 * cnt[b]) + bv;
  }
}

extern "C" void kernel_launch(void* const* d_in, const int* in_sizes, int n_in,
                              void* d_out, int out_size, void* d_ws, size_t ws_size,
                              hipStream_t stream) {
  const u32x4* x = (const u32x4*)d_in[0];  // fp32 bits of input [8,8192]
  const u32x4* W = (const u32x4*)d_in[1];  // fp32 bits of weight [8192,8192]
  const float* bias = (const float*)d_in[2];
  float* out = (float*)d_out;              // [8,8192]
  (void)d_ws; (void)ws_size;

  ternary_fused<<<OUT_F / 4, 256, 0, stream>>>(W, x, bias, out);
}

// Round 5
// 49.691 us; speedup vs baseline: 1.2057x; 1.2057x over previous
//
#include <hip/hip_runtime.h>
#include <stdint.h>

#define IN_F 8192
#define OUT_F 8192
#define BATCH 8
// Permuted x sign-bit layout, matched to the gemv's lane order:
//   word[(b*4 + m)*64 + l], bit (4*i + k) = signbit(x[b*8192 + m*2048 + i*256 + l*4 + k])
#define XPW (BATCH * 4 * 64)  // 2048 words = 8 KB

typedef unsigned int u32x4 __attribute__((ext_vector_type(4)));

__global__ __launch_bounds__(256) void pack_sign_perm(
    const u32x4* __restrict__ x, uint32_t* __restrict__ xp) {
  const int t = blockIdx.x * 256 + threadIdx.x;  // 0..2047
  const int b = t >> 8;
  const int m = (t >> 6) & 3;
  const int l = t & 63;
  const u32x4* base = x + (b * IN_F + m * 2048 + l * 4) / 4;
  uint32_t w = 0;
#pragma unroll
  for (int i = 0; i < 8; ++i) {
    u32x4 u = base[i * 64];
    uint32_t nib = (u.x >> 31) | ((u.y >> 31) << 1) |
                   ((u.z >> 31) << 2) | ((u.w >> 31) << 3);
    w |= nib << (4 * i);
  }
  xp[t] = w;
}

// One wave per output row, no LDS, no barrier. Per 8-KB macro-tile m:
// 8 NT uint4 W-loads -> 32 sign bits; 8 cached dword loads of the permuted
// x words (L1-resident, coalesced); 8x xor+popcount accumulate.
__global__ __launch_bounds__(256) void ternary_gemv3(
    const u32x4* __restrict__ W, const uint32_t* __restrict__ xp,
    const float* __restrict__ bias, float* __restrict__ out) {
  const int warp = threadIdx.x >> 6;
  const int lane = threadIdx.x & 63;
  const int row = blockIdx.x * 4 + warp;
  const u32x4* wrow = W + (size_t)row * (IN_F / 4);

  int cnt[BATCH] = {0, 0, 0, 0, 0, 0, 0, 0};

#pragma unroll
  for (int m = 0; m < 4; ++m) {
    u32x4 u[8];
#pragma unroll
    for (int i = 0; i < 8; ++i)
      u[i] = __builtin_nontemporal_load(&wrow[m * 512 + i * 64 + lane]);

    uint32_t xn[BATCH];
#pragma unroll
    for (int b = 0; b < BATCH; ++b)
      xn[b] = xp[(b * 4 + m) * 64 + lane];

    uint32_t wn = 0;
#pragma unroll
    for (int i = 0; i < 8; ++i) {
      uint32_t nib = (u[i].x >> 31) | ((u[i].y >> 31) << 1) |
                     ((u[i].z >> 31) << 2) | ((u[i].w >> 31) << 3);
      wn |= nib << (4 * i);
    }

#pragma unroll
    for (int b = 0; b < BATCH; ++b)
      cnt[b] += __popc(wn ^ xn[b]);
  }

  // Wave-level reduce of the 8 mismatch counts.
#pragma unroll
  for (int b = 0; b < BATCH; ++b) {
#pragma unroll
    for (int off = 32; off > 0; off >>= 1)
      cnt[b] += __shfl_down(cnt[b], off);
  }

  if (lane == 0) {
    const float bv = bias[row];
#pragma unroll
    for (int b = 0; b < BATCH; ++b)
      out[(size_t)b * OUT_F + row] = (float)(IN_F - 2 * cnt[b]) + bv;
  }
}

extern "C" void kernel_launch(void* const* d_in, const int* in_sizes, int n_in,
                              void* d_out, int out_size, void* d_ws, size_t ws_size,
                              hipStream_t stream) {
  const u32x4* x = (const u32x4*)d_in[0];  // fp32 bits of input [8,8192]
  const u32x4* W = (const u32x4*)d_in[1];  // fp32 bits of weight [8192,8192]
  const float* bias = (const float*)d_in[2];
  float* out = (float*)d_out;              // [8,8192]
  uint32_t* xp = (uint32_t*)d_ws;          // 8 KB permuted sign bits

  pack_sign_perm<<<XPW / 256, 256, 0, stream>>>(x, xp);
  ternary_gemv3<<<OUT_F / 4, 256, 0, stream>>>(W, xp, bias, out);
}